// Round 13
// baseline (182.658 us; speedup 1.0000x reference)
//
#include <hip/hip_runtime.h>

#define B_ 4
#define S_ 2048
#define D_ 768
#define H_ 12
#define HD_ 64
#define T_ (B_ * S_)  // 8192

typedef __bf16 bf16x8 __attribute__((ext_vector_type(8)));
typedef __bf16 bf16x4 __attribute__((ext_vector_type(4)));
typedef float  f32x4  __attribute__((ext_vector_type(4)));

__device__ __forceinline__ f32x4 mfma16(bf16x8 a, bf16x8 b, f32x4 c) {
  return __builtin_amdgcn_mfma_f32_16x16x32_bf16(a, b, c, 0, 0, 0);
}

// 2^x via v_exp_f32 (scores are pre-scaled by log2e at weight-convert time)
__device__ __forceinline__ float fexp2(float x) {
  float r;
  asm("v_exp_f32 %0, %1" : "=v"(r) : "v"(x));
  return r;
}

// async global->LDS, 16B per lane. LDS dest is wave-uniform base + lane*16.
__device__ __forceinline__ void gload16(const __bf16* g, __bf16* lds) {
  __builtin_amdgcn_global_load_lds(
      (__attribute__((address_space(1))) void*)g,
      (__attribute__((address_space(3))) void*)lds, 16, 0, 0);
}

// ---------------- fp32 -> bf16 convert (vectorized, optional scale) ----------
__global__ void cvt_f32_bf16(const float* __restrict__ in, __bf16* __restrict__ out,
                             int n4, float scale) {
  int i = blockIdx.x * blockDim.x + threadIdx.x;
  if (i >= n4) return;
  float4 v = reinterpret_cast<const float4*>(in)[i];
  bf16x4 o;
  o[0] = (__bf16)(v.x * scale);
  o[1] = (__bf16)(v.y * scale);
  o[2] = (__bf16)(v.z * scale);
  o[3] = (__bf16)(v.w * scale);
  reinterpret_cast<bf16x4*>(out)[i] = o;
}

// ---------------- 256x256 GEMM, XCD-clustered (C = A * W^T) ------------------
// Rounds 9-12 lesson: the 128-tile GEMM was L3-supply-bound (~5 TB/s staging,
// T_block ~29 us, MfmaUtil pinned at 12.5% across 4 structural variants) —
// blocks sharing operand panels were scattered across XCDs, so ~all staging
// missed the 4 MB per-XCD L2. Fix: (1) 256x256 tile (staged bytes x0.67),
// (2) XCD-clustered mapping: xcd = bx&7 owns a contiguous 1024-row A slab
// (1.5 MB, L2-resident, shared by its concurrent blocks) and walks n-panels
// slowly (each 384 KB B panel pulled from L3 once, L2-hit by the other 3
// blocks on the same XCD). 8 waves (2Mx4N), per-wave 128x64 out, BK=64,
// counted-vmcnt 2-deep pipeline, XOR-swizzled LDS.
// MODE 0: QKV over combined N=2304 (W = wq|wk|wv); scatter epilogue.
// MODE 1: output projection N=768, fp32 + bias epilogue.
template <int MODE>
__global__ __launch_bounds__(512)
__attribute__((amdgpu_waves_per_eu(2, 2)))
void gemm256(const __bf16* __restrict__ A, const __bf16* __restrict__ W,
             __bf16* __restrict__ Oq, __bf16* __restrict__ Ok,
             __bf16* __restrict__ Ov,
             float* __restrict__ fout, const float* __restrict__ bias) {
  constexpr int K = D_;       // 768
  constexpr int NT = K / 64;  // 12 K-tiles
  __shared__ __align__(16) __bf16 sA[2][256 * 64];  // 32 KB x2
  __shared__ __align__(16) __bf16 sB[2][256 * 64];  // 32 KB x2

  const int tid = threadIdx.x;
  const int l = tid & 63;
  const int w = tid >> 6;  // 0..7
  const int bx = blockIdx.x;
  const int xcd = bx & 7;
  const int i = bx >> 3;             // [0, 4*NPANEL)
  const int ntile = i >> 2;          // n-panel, panel-major per XCD
  const int mtile = xcd * 4 + (i & 3);  // contiguous M slab per XCD
  const int m0 = mtile * 256;
  const int n0g = ntile * 256;

  // staging: 32 chunks of 8 rows x 64 k (1 KB) for A and for B; wave w stages
  // chunks 4w..4w+3 of each. Lane l -> row c*8+(l>>3), 16B slot (l&7); source
  // col pre-swizzled so LDS[r][slot] = G[r][slot ^ (r&7)].
  const int srow = l >> 3;                // 0..7
  const int scol = ((l & 7) ^ srow) * 8;  // source col (elements)
  const __bf16* gA[4];
  const __bf16* gB[4];
#pragma unroll
  for (int c = 0; c < 4; ++c) {
    const int ch = w * 4 + c;
    gA[c] = A + (size_t)(m0 + ch * 8 + srow) * K + scol;
    gB[c] = W + (size_t)(n0g + ch * 8 + srow) * K + scol;
  }

  f32x4 acc[8][4] = {};
  const int wr = w >> 2, wc = w & 3;  // wave grid 2(M) x 4(N)
  const int fr = l & 15, fq = l >> 4;
  const int swz = (fr & 7) << 4;

  // prologue: stage K-tiles 0 and 1 (8 loads/wave each; 16 in flight)
#pragma unroll
  for (int b = 0; b < 2; ++b) {
#pragma unroll
    for (int c = 0; c < 4; ++c) {
      const int ch = w * 4 + c;
      gload16(gA[c] + b * 64, &sA[b][ch * 512]);
      gload16(gB[c] + b * 64, &sB[b][ch * 512]);
    }
  }

  int cur = 0;
  for (int kt = 0; kt < NT; ++kt) {
    // wait for OWN stage(kt) only; stage(kt+1)'s 8 loads stay in flight
    if (kt + 1 < NT)
      asm volatile("s_waitcnt vmcnt(8)" ::: "memory");
    else
      asm volatile("s_waitcnt vmcnt(0)" ::: "memory");
    __builtin_amdgcn_s_barrier();  // all waves' stage(kt) landed

    const char* ab = reinterpret_cast<const char*>(&sA[cur][0]);
    const char* bb = reinterpret_cast<const char*>(&sB[cur][0]);
#pragma unroll
    for (int ks = 0; ks < 2; ++ks) {
      bf16x8 af[8], bfr[4];
#pragma unroll
      for (int mi = 0; mi < 8; ++mi)
        af[mi] = *reinterpret_cast<const bf16x8*>(
            ab + (wr * 128 + mi * 16 + fr) * 128 +
            ((ks * 64 + fq * 16) ^ swz));
#pragma unroll
      for (int ni = 0; ni < 4; ++ni)
        bfr[ni] = *reinterpret_cast<const bf16x8*>(
            bb + (wc * 64 + ni * 16 + fr) * 128 +
            ((ks * 64 + fq * 16) ^ swz));
      __builtin_amdgcn_s_setprio(1);
#pragma unroll
      for (int mi = 0; mi < 8; ++mi)
#pragma unroll
        for (int ni = 0; ni < 4; ++ni)
          acc[mi][ni] = mfma16(af[mi], bfr[ni], acc[mi][ni]);
      __builtin_amdgcn_s_setprio(0);
    }
    __builtin_amdgcn_s_barrier();  // all waves done reading buf[cur]

    // stage kt+2 into the freed buffer
    if (kt + 2 < NT) {
      const int ko = (kt + 2) * 64;
#pragma unroll
      for (int c = 0; c < 4; ++c) {
        const int ch = w * 4 + c;
        gload16(gA[c] + ko, &sA[cur][ch * 512]);
        gload16(gB[c] + ko, &sB[cur][ch * 512]);
      }
    }
    cur ^= 1;
  }

  // epilogue
#pragma unroll
  for (int mi = 0; mi < 8; ++mi) {
    const int mbase = m0 + wr * 128 + mi * 16 + fq * 4;
#pragma unroll
    for (int ni = 0; ni < 4; ++ni) {
      if (MODE == 1) {
        const int o = n0g + wc * 64 + ni * 16 + fr;  // [0, 768)
#pragma unroll
        for (int r = 0; r < 4; ++r)
          fout[(size_t)(mbase + r) * D_ + o] = acc[mi][ni][r] + bias[o];
      } else {
        const int mat = ntile / 3;                       // 0=Q 1=K 2=V
        const int o = (ntile % 3) * 256 + wc * 64 + ni * 16 + fr;  // [0,768)
        const int h = o >> 6, hd = o & 63;
#pragma unroll
        for (int r = 0; r < 4; ++r) {
          const float v = acc[mi][ni][r];
          const int mm = mbase + r;
          const int b = mm >> 11, s = mm & (S_ - 1);
          if (mat == 0)
            Oq[((size_t)((b * H_ + h) * S_ + s)) * HD_ + hd] = (__bf16)v;
          else if (mat == 1)
            Ok[((size_t)((b * H_ + h) * S_ + s)) * HD_ + hd] = (__bf16)v;
          else
            Ov[((size_t)((b * H_ + h) * HD_ + hd)) * S_ + s] = (__bf16)v;
        }
      }
    }
  }
}

// ---------------- causal flash attention: 4-warp block, LDS-staged K/V --------
// (unchanged from round 12)
__global__ __launch_bounds__(256)
__attribute__((amdgpu_waves_per_eu(3, 4)))
void attn_kernel(const __bf16* __restrict__ Q, const __bf16* __restrict__ Kt,
                 const __bf16* __restrict__ Vt, __bf16* __restrict__ C) {
  __shared__ __align__(16) __bf16 sK[2][64 * 64];  // [kv][hd], swizzled
  __shared__ __align__(16) __bf16 sV[2][64 * 64];  // V^T [hd][kv], swizzled
  __shared__ __align__(16) __bf16 sP[4][32 * 64];  // per-warp P, swizzled

  const int tid = threadIdx.x;
  const int l = tid & 63;
  const int w = tid >> 6;
  const int fr = l & 15, fq = l >> 4;
  const int bx = blockIdx.x;
  const int xcd = bx & 7;
  const int j = bx >> 3;             // [0, 96)
  const int bh = xcd + 8 * (j % 6);  // head in [0, 48)
  const int qtile = 15 - j / 6;      // [0, 16), deep first
  const int qb = qtile * 128;
  const int qbw = qb + w * 32;  // this warp's 32 q-rows

  const __bf16* qh = Q + (size_t)bh * S_ * HD_;
  const __bf16* kh = Kt + (size_t)bh * S_ * HD_;
  const __bf16* vh = Vt + (size_t)bh * HD_ * S_;
  char* sPb = reinterpret_cast<char*>(&sP[w][0]);

  const int srow = l >> 3;                       // 0..7
  const int scol = ((l & 7) * 8) ^ (srow << 3);  // pre-swizzled source col
  const int swz = (fr & 7) << 4;                 // read-side XOR (bytes)

  bf16x8 qf[2][2];
#pragma unroll
  for (int g = 0; g < 2; ++g)
#pragma unroll
    for (int ks = 0; ks < 2; ++ks)
      qf[g][ks] = *reinterpret_cast<const bf16x8*>(
          &qh[(size_t)(qbw + g * 16 + fr) * HD_ + ks * 32 + fq * 8]);

  f32x4 acc[2][4] = {};
  float mrow[2] = {-1e30f, -1e30f}, lrow[2] = {0.f, 0.f};

  const int nt = qb / 64 + 2;  // ceil((qb+128)/64)
  int cur = 0;

  {
    const int q0 = 2 * w, q1 = 2 * w + 1;
    gload16(kh + (size_t)(q0 * 8 + srow) * HD_ + scol, &sK[0][q0 * 512]);
    gload16(kh + (size_t)(q1 * 8 + srow) * HD_ + scol, &sK[0][q1 * 512]);
    gload16(vh + (size_t)(q0 * 8 + srow) * S_ + scol, &sV[0][q0 * 512]);
    gload16(vh + (size_t)(q1 * 8 + srow) * S_ + scol, &sV[0][q1 * 512]);
  }
  __syncthreads();

  for (int t = 0; t < nt; ++t) {
    const int kv0 = t * 64;
    if (t + 1 < nt) {
      const int kvn = kv0 + 64;
      const int q0 = 2 * w, q1 = 2 * w + 1;
      gload16(kh + (size_t)(kvn + q0 * 8 + srow) * HD_ + scol,
              &sK[cur ^ 1][q0 * 512]);
      gload16(kh + (size_t)(kvn + q1 * 8 + srow) * HD_ + scol,
              &sK[cur ^ 1][q1 * 512]);
      gload16(vh + (size_t)(q0 * 8 + srow) * S_ + kvn + scol,
              &sV[cur ^ 1][q0 * 512]);
      gload16(vh + (size_t)(q1 * 8 + srow) * S_ + kvn + scol,
              &sV[cur ^ 1][q1 * 512]);
    }

    if (kv0 <= qbw + 31) {
      const char* kb = reinterpret_cast<const char*>(&sK[cur][0]);
      const char* vb = reinterpret_cast<const char*>(&sV[cur][0]);

      f32x4 s[2][4];
      __builtin_amdgcn_s_setprio(1);
#pragma unroll
      for (int c = 0; c < 4; ++c) {
        const int row = c * 16 + fr;
        bf16x8 kf0 = *reinterpret_cast<const bf16x8*>(
            kb + row * 128 + ((fq * 16) ^ swz));
        bf16x8 kf1 = *reinterpret_cast<const bf16x8*>(
            kb + row * 128 + ((fq * 16 + 64) ^ swz));
#pragma unroll
        for (int g = 0; g < 2; ++g) {
          f32x4 z = {};
          z = mfma16(kf0, qf[g][0], z);
          z = mfma16(kf1, qf[g][1], z);
          s[g][c] = z;
        }
      }
      __builtin_amdgcn_s_setprio(0);

      if (kv0 + 63 > qbw) {
#pragma unroll
        for (int g = 0; g < 2; ++g) {
          const int qi = qbw + g * 16 + fr;
#pragma unroll
          for (int c = 0; c < 4; ++c)
#pragma unroll
            for (int r = 0; r < 4; ++r) {
              const int kvi = kv0 + c * 16 + fq * 4 + r;
              if (kvi > qi) s[g][c][r] = -1e30f;
            }
        }
      }

#pragma unroll
      for (int g = 0; g < 2; ++g) {
        float tm = -1e30f;
#pragma unroll
        for (int c = 0; c < 4; ++c)
#pragma unroll
          for (int r = 0; r < 4; ++r) tm = fmaxf(tm, s[g][c][r]);
        tm = fmaxf(tm, __shfl_xor(tm, 16));
        tm = fmaxf(tm, __shfl_xor(tm, 32));
        const float mn = fmaxf(mrow[g], tm);
        const float fac = fexp2(mrow[g] - mn);  // log2-domain
        mrow[g] = mn;
        float sum = 0.f;
#pragma unroll
        for (int c = 0; c < 4; ++c) {
          bf16x4 pc;
#pragma unroll
          for (int r = 0; r < 4; ++r) {
            const float p = fexp2(s[g][c][r] - mn);
            sum += p;
            pc[r] = (__bf16)p;
          }
          const int bo = (c * 32 + fq * 8) ^ swz;
          *reinterpret_cast<bf16x4*>(sPb + (g * 16 + fr) * 128 + bo) = pc;
        }
        sum += __shfl_xor(sum, 16);
        sum += __shfl_xor(sum, 32);
        lrow[g] = lrow[g] * fac + sum;
#pragma unroll
        for (int dt = 0; dt < 4; ++dt)
#pragma unroll
          for (int r = 0; r < 4; ++r) acc[g][dt][r] *= fac;

        bf16x8 pa[2];
#pragma unroll
        for (int ks = 0; ks < 2; ++ks) {
          const int bo = (ks * 64 + fq * 16) ^ swz;
          pa[ks] = *reinterpret_cast<const bf16x8*>(sPb +
                                                    (g * 16 + fr) * 128 + bo);
        }

        __builtin_amdgcn_s_setprio(1);
#pragma unroll
        for (int dt = 0; dt < 4; ++dt) {
          const int row = dt * 16 + fr;
          bf16x8 vf0 = *reinterpret_cast<const bf16x8*>(
              vb + row * 128 + ((fq * 16) ^ swz));
          bf16x8 vf1 = *reinterpret_cast<const bf16x8*>(
              vb + row * 128 + ((fq * 16 + 64) ^ swz));
          acc[g][dt] = mfma16(vf0, pa[0], acc[g][dt]);
          acc[g][dt] = mfma16(vf1, pa[1], acc[g][dt]);
        }
        __builtin_amdgcn_s_setprio(0);
      }
    }

    __syncthreads();
    cur ^= 1;
  }

  const int b = bh / H_, h = bh % H_;
#pragma unroll
  for (int g = 0; g < 2; ++g) {
    const float inv_l = 1.0f / lrow[g];
    const int qrow = qbw + g * 16 + fr;
#pragma unroll
    for (int dt = 0; dt < 4; ++dt) {
      bf16x4 ov;
#pragma unroll
      for (int r = 0; r < 4; ++r) ov[r] = (__bf16)(acc[g][dt][r] * inv_l);
      *reinterpret_cast<bf16x4*>(
          &C[((size_t)(b * S_ + qrow)) * D_ + h * HD_ + dt * 16 + fq * 4]) =
          ov;
    }
  }
}

// ---------------- workspace layout (bf16 elements) ---------------------------
static constexpr size_t XB_OFF = 0;
static constexpr size_t WQ_OFF = XB_OFF + (size_t)T_ * D_;
static constexpr size_t WK_OFF = WQ_OFF + (size_t)D_ * D_;  // contiguous after
static constexpr size_t WV_OFF = WK_OFF + (size_t)D_ * D_;  // wq (combined W)
static constexpr size_t WO_OFF = WV_OFF + (size_t)D_ * D_;
static constexpr size_t Q_OFF = WO_OFF + (size_t)D_ * D_;
static constexpr size_t K_OFF = Q_OFF + (size_t)T_ * D_;
static constexpr size_t V_OFF = K_OFF + (size_t)T_ * D_;
static constexpr size_t C_OFF = V_OFF + (size_t)T_ * D_;

extern "C" void kernel_launch(void* const* d_in, const int* in_sizes, int n_in,
                              void* d_out, int out_size, void* d_ws,
                              size_t ws_size, hipStream_t stream) {
  const float* x = (const float*)d_in[0];
  const float* wq = (const float*)d_in[1];
  const float* wk = (const float*)d_in[2];
  const float* wv = (const float*)d_in[3];
  const float* wo = (const float*)d_in[4];
  const float* bo = (const float*)d_in[5];
  float* out = (float*)d_out;
  __bf16* ws = (__bf16*)d_ws;

  __bf16* xb = ws + XB_OFF;
  __bf16* wqb = ws + WQ_OFF;  // combined W base: rows 0..767 Q, ..K, ..V
  __bf16* wkb = ws + WK_OFF;
  __bf16* wvb = ws + WV_OFF;
  __bf16* wob = ws + WO_OFF;
  __bf16* qbuf = ws + Q_OFF;
  __bf16* kbuf = ws + K_OFF;
  __bf16* vbuf = ws + V_OFF;
  __bf16* cbuf = ws + C_OFF;

  {
    int n4 = T_ * D_ / 4;
    cvt_f32_bf16<<<(n4 + 255) / 256, 256, 0, stream>>>(x, xb, n4, 1.0f);
    n4 = D_ * D_ / 4;
    cvt_f32_bf16<<<(n4 + 255) / 256, 256, 0, stream>>>(wq, wqb, n4, 1.0f);
    // fold 1/sqrt(64) * log2(e) into K: scores emerge in log2-domain
    cvt_f32_bf16<<<(n4 + 255) / 256, 256, 0, stream>>>(wk, wkb, n4,
                                                       0.18033688f);
    cvt_f32_bf16<<<(n4 + 255) / 256, 256, 0, stream>>>(wv, wvb, n4, 1.0f);
    cvt_f32_bf16<<<(n4 + 255) / 256, 256, 0, stream>>>(wo, wob, n4, 1.0f);
  }

  // QKV: 32 mtiles x 9 panels, XCD-clustered
  gemm256<0><<<dim3(288), 512, 0, stream>>>(xb, wqb, qbuf, kbuf, vbuf,
                                            nullptr, nullptr);

  attn_kernel<<<dim3(768), 256, 0, stream>>>(qbuf, kbuf, vbuf, cbuf);

  // out-proj: 32 mtiles x 3 panels
  gemm256<1><<<dim3(96), 512, 0, stream>>>(cbuf, wob, nullptr, nullptr,
                                           nullptr, out, bo);
}

// Round 14
// 147.193 us; speedup vs baseline: 1.2409x; 1.2409x over previous
//
#include <hip/hip_runtime.h>

#define B_ 4
#define S_ 2048
#define D_ 768
#define H_ 12
#define HD_ 64
#define T_ (B_ * S_)  // 8192

typedef __bf16 bf16x8 __attribute__((ext_vector_type(8)));
typedef __bf16 bf16x4 __attribute__((ext_vector_type(4)));
typedef float  f32x4  __attribute__((ext_vector_type(4)));

__device__ __forceinline__ f32x4 mfma16(bf16x8 a, bf16x8 b, f32x4 c) {
  return __builtin_amdgcn_mfma_f32_16x16x32_bf16(a, b, c, 0, 0, 0);
}

// 2^x via v_exp_f32 (scores are pre-scaled by log2e at weight-convert time)
__device__ __forceinline__ float fexp2(float x) {
  float r;
  asm("v_exp_f32 %0, %1" : "=v"(r) : "v"(x));
  return r;
}

// async global->LDS, 16B per lane. LDS dest is wave-uniform base + lane*16.
__device__ __forceinline__ void gload16(const __bf16* g, __bf16* lds) {
  __builtin_amdgcn_global_load_lds(
      (__attribute__((address_space(1))) void*)g,
      (__attribute__((address_space(3))) void*)lds, 16, 0, 0);
}

// ---------------- fp32 -> bf16 convert (vectorized, optional scale) ----------
__global__ void cvt_f32_bf16(const float* __restrict__ in, __bf16* __restrict__ out,
                             int n4, float scale) {
  int i = blockIdx.x * blockDim.x + threadIdx.x;
  if (i >= n4) return;
  float4 v = reinterpret_cast<const float4*>(in)[i];
  bf16x4 o;
  o[0] = (__bf16)(v.x * scale);
  o[1] = (__bf16)(v.y * scale);
  o[2] = (__bf16)(v.z * scale);
  o[3] = (__bf16)(v.w * scale);
  reinterpret_cast<bf16x4*>(out)[i] = o;
}

// ---------------- GEMM: C[m][n] = sum_k A[m][k] * W[n][k]  (B^T layout) ------
// Round-11 structure (best measured) + XCD-slab remap (round-14):
// flat = by*64+bx (HW dispatch order), xcd = flat&7 -> each XCD owns a
// contiguous 8-m-tile A slab (1.5 MB, L2-resident, re-read from L2 instead of
// L3) and walks n-panels slowest -> concurrent working set per XCD ~1.9 MB
// fits the 4 MB L2. r9-r13 lesson: staging from L3 caps at ~5 TB/s; from L2
// it doesn't (m97@4096 sustains ~13 TB/s). 128x128 tile, BK=64, 2-deep
// counted-vmcnt pipeline, XOR-swizzled LDS.
template <int MODE>
__global__ __launch_bounds__(256)
__attribute__((amdgpu_waves_per_eu(2)))
void gemm_bt(const __bf16* __restrict__ A,
             const __bf16* __restrict__ W0, const __bf16* __restrict__ W1,
             const __bf16* __restrict__ W2,
             __bf16* __restrict__ Oq, __bf16* __restrict__ Ok,
             __bf16* __restrict__ Ov,
             float* __restrict__ fout, const float* __restrict__ bias) {
  constexpr int K = D_;       // 768
  constexpr int NT = K / 64;  // 12 K-tiles
  __shared__ __align__(16) __bf16 sA[2][128 * 64];
  __shared__ __align__(16) __bf16 sB[2][128 * 64];

  const int tid = threadIdx.x;
  const int l = tid & 63;
  const int w = tid >> 6;

  // XCD-slab remap: mtile = xcd*8 + (q&7) (contiguous 1024-row A slab per
  // XCD), panel = q>>3 changes slowest (panel-major in time per XCD).
  const int flat = blockIdx.y * 64 + blockIdx.x;
  const int xcd = flat & 7;
  const int q = flat >> 3;
  const int mtile = xcd * 8 + (q & 7);
  const int pan = q >> 3;  // [0,18) MODE0, [0,6) MODE1
  const int m0 = mtile * 128;

  int mat, n0;
  const __bf16* Wm;
  if (MODE == 0) {
    mat = pan / 6;
    n0 = (pan % 6) * 128;
    Wm = (mat == 0) ? W0 : (mat == 1) ? W1 : W2;
  } else {
    mat = 0;
    n0 = pan * 128;
    Wm = W0;
  }

  // staging: chunk c (0..15) = rows [c*8, c*8+8) x 64 k (1 KB). Wave w stages
  // chunks 4w..4w+3 of A and B. Lane l -> row c*8 + (l>>3), 16B slot (l&7);
  // source col pre-swizzled so LDS[r][slot] = G[r][slot ^ (r&7)].
  const int srow = l >> 3;                // 0..7
  const int scol = ((l & 7) ^ srow) * 8;  // source col (elements)
  const __bf16* gA[4];
  const __bf16* gB[4];
#pragma unroll
  for (int i = 0; i < 4; ++i) {
    const int c = w * 4 + i;
    gA[i] = A + (size_t)(m0 + c * 8 + srow) * K + scol;
    gB[i] = Wm + (size_t)(n0 + c * 8 + srow) * K + scol;
  }

  f32x4 acc[4][4] = {};
  const int wr = w >> 1, wc = w & 1;
  const int fr = l & 15, fq = l >> 4;
  const int swz = (fr & 7) << 4;

  // prologue: stage K-tiles 0 and 1 (16 loads/wave in flight)
#pragma unroll
  for (int i = 0; i < 4; ++i) {
    const int c = w * 4 + i;
    gload16(gA[i], &sA[0][c * 512]);
    gload16(gB[i], &sB[0][c * 512]);
  }
#pragma unroll
  for (int i = 0; i < 4; ++i) {
    const int c = w * 4 + i;
    gload16(gA[i] + 64, &sA[1][c * 512]);
    gload16(gB[i] + 64, &sB[1][c * 512]);
  }

  int cur = 0;
  for (int kt = 0; kt < NT; ++kt) {
    // wait for OWN stage(kt) only; stage(kt+1) stays in flight (counted vmcnt)
    if (kt + 1 < NT)
      asm volatile("s_waitcnt vmcnt(8)" ::: "memory");
    else
      asm volatile("s_waitcnt vmcnt(0)" ::: "memory");
    __builtin_amdgcn_s_barrier();  // all waves' stage(kt) landed

    const char* ab = reinterpret_cast<const char*>(&sA[cur][0]);
    const char* bb = reinterpret_cast<const char*>(&sB[cur][0]);
#pragma unroll
    for (int ks = 0; ks < 2; ++ks) {
      bf16x8 af[4], bfr[4];
#pragma unroll
      for (int mi = 0; mi < 4; ++mi)
        af[mi] = *reinterpret_cast<const bf16x8*>(
            ab + (wr * 64 + mi * 16 + fr) * 128 +
            ((ks * 64 + fq * 16) ^ swz));
#pragma unroll
      for (int ni = 0; ni < 4; ++ni)
        bfr[ni] = *reinterpret_cast<const bf16x8*>(
            bb + (wc * 64 + ni * 16 + fr) * 128 +
            ((ks * 64 + fq * 16) ^ swz));
#pragma unroll
      for (int mi = 0; mi < 4; ++mi)
#pragma unroll
        for (int ni = 0; ni < 4; ++ni)
          acc[mi][ni] = mfma16(af[mi], bfr[ni], acc[mi][ni]);
    }
    __builtin_amdgcn_s_barrier();  // all waves done reading buf[cur]

    // stage kt+2 into the buffer just freed (2-deep pipeline)
    if (kt + 2 < NT) {
      const int ko = (kt + 2) * 64;
#pragma unroll
      for (int i = 0; i < 4; ++i) {
        const int c = w * 4 + i;
        gload16(gA[i] + ko, &sA[cur][c * 512]);
        gload16(gB[i] + ko, &sB[cur][c * 512]);
      }
    }
    cur ^= 1;
  }

#pragma unroll
  for (int mi = 0; mi < 4; ++mi) {
    const int mbase = m0 + wr * 64 + mi * 16 + fq * 4;
#pragma unroll
    for (int ni = 0; ni < 4; ++ni) {
      const int o = n0 + wc * 64 + ni * 16 + fr;
#pragma unroll
      for (int r = 0; r < 4; ++r) {
        const float v = acc[mi][ni][r];
        const int mm = mbase + r;
        if (MODE == 1) {
          fout[mm * D_ + o] = v + bias[o];
        } else {
          const int b = mm >> 11, s = mm & (S_ - 1);
          const int h = o >> 6, hd = o & 63;
          if (mat == 0)
            Oq[((size_t)((b * H_ + h) * S_ + s)) * HD_ + hd] = (__bf16)v;
          else if (mat == 1)
            Ok[((size_t)((b * H_ + h) * S_ + s)) * HD_ + hd] = (__bf16)v;
          else
            Ov[((size_t)((b * H_ + h) * HD_ + hd)) * S_ + s] = (__bf16)v;
        }
      }
    }
  }
}

// ---------------- causal flash attention: 4-warp block, LDS-staged K/V --------
// (unchanged from round 11)
__global__ __launch_bounds__(256)
__attribute__((amdgpu_waves_per_eu(3, 4)))
void attn_kernel(const __bf16* __restrict__ Q, const __bf16* __restrict__ Kt,
                 const __bf16* __restrict__ Vt, __bf16* __restrict__ C) {
  __shared__ __align__(16) __bf16 sK[2][64 * 64];  // [kv][hd], swizzled
  __shared__ __align__(16) __bf16 sV[2][64 * 64];  // V^T [hd][kv], swizzled
  __shared__ __align__(16) __bf16 sP[4][32 * 64];  // per-warp P, swizzled

  const int tid = threadIdx.x;
  const int l = tid & 63;
  const int w = tid >> 6;
  const int fr = l & 15, fq = l >> 4;
  const int bx = blockIdx.x;
  const int xcd = bx & 7;
  const int j = bx >> 3;             // [0, 96)
  const int bh = xcd + 8 * (j % 6);  // head in [0, 48)
  const int qtile = 15 - j / 6;      // [0, 16), deep first
  const int qb = qtile * 128;
  const int qbw = qb + w * 32;  // this warp's 32 q-rows

  const __bf16* qh = Q + (size_t)bh * S_ * HD_;
  const __bf16* kh = Kt + (size_t)bh * S_ * HD_;
  const __bf16* vh = Vt + (size_t)bh * HD_ * S_;
  char* sPb = reinterpret_cast<char*>(&sP[w][0]);

  const int srow = l >> 3;                       // 0..7
  const int scol = ((l & 7) * 8) ^ (srow << 3);  // pre-swizzled source col
  const int swz = (fr & 7) << 4;                 // read-side XOR (bytes)

  bf16x8 qf[2][2];
#pragma unroll
  for (int g = 0; g < 2; ++g)
#pragma unroll
    for (int ks = 0; ks < 2; ++ks)
      qf[g][ks] = *reinterpret_cast<const bf16x8*>(
          &qh[(size_t)(qbw + g * 16 + fr) * HD_ + ks * 32 + fq * 8]);

  f32x4 acc[2][4] = {};
  float mrow[2] = {-1e30f, -1e30f}, lrow[2] = {0.f, 0.f};

  const int nt = qb / 64 + 2;  // ceil((qb+128)/64)
  int cur = 0;

  {
    const int q0 = 2 * w, q1 = 2 * w + 1;
    gload16(kh + (size_t)(q0 * 8 + srow) * HD_ + scol, &sK[0][q0 * 512]);
    gload16(kh + (size_t)(q1 * 8 + srow) * HD_ + scol, &sK[0][q1 * 512]);
    gload16(vh + (size_t)(q0 * 8 + srow) * S_ + scol, &sV[0][q0 * 512]);
    gload16(vh + (size_t)(q1 * 8 + srow) * S_ + scol, &sV[0][q1 * 512]);
  }
  __syncthreads();

  for (int t = 0; t < nt; ++t) {
    const int kv0 = t * 64;
    if (t + 1 < nt) {
      const int kvn = kv0 + 64;
      const int q0 = 2 * w, q1 = 2 * w + 1;
      gload16(kh + (size_t)(kvn + q0 * 8 + srow) * HD_ + scol,
              &sK[cur ^ 1][q0 * 512]);
      gload16(kh + (size_t)(kvn + q1 * 8 + srow) * HD_ + scol,
              &sK[cur ^ 1][q1 * 512]);
      gload16(vh + (size_t)(q0 * 8 + srow) * S_ + kvn + scol,
              &sV[cur ^ 1][q0 * 512]);
      gload16(vh + (size_t)(q1 * 8 + srow) * S_ + kvn + scol,
              &sV[cur ^ 1][q1 * 512]);
    }

    if (kv0 <= qbw + 31) {
      const char* kb = reinterpret_cast<const char*>(&sK[cur][0]);
      const char* vb = reinterpret_cast<const char*>(&sV[cur][0]);

      f32x4 s[2][4];
      __builtin_amdgcn_s_setprio(1);
#pragma unroll
      for (int c = 0; c < 4; ++c) {
        const int row = c * 16 + fr;
        bf16x8 kf0 = *reinterpret_cast<const bf16x8*>(
            kb + row * 128 + ((fq * 16) ^ swz));
        bf16x8 kf1 = *reinterpret_cast<const bf16x8*>(
            kb + row * 128 + ((fq * 16 + 64) ^ swz));
#pragma unroll
        for (int g = 0; g < 2; ++g) {
          f32x4 z = {};
          z = mfma16(kf0, qf[g][0], z);
          z = mfma16(kf1, qf[g][1], z);
          s[g][c] = z;
        }
      }
      __builtin_amdgcn_s_setprio(0);

      if (kv0 + 63 > qbw) {
#pragma unroll
        for (int g = 0; g < 2; ++g) {
          const int qi = qbw + g * 16 + fr;
#pragma unroll
          for (int c = 0; c < 4; ++c)
#pragma unroll
            for (int r = 0; r < 4; ++r) {
              const int kvi = kv0 + c * 16 + fq * 4 + r;
              if (kvi > qi) s[g][c][r] = -1e30f;
            }
        }
      }

#pragma unroll
      for (int g = 0; g < 2; ++g) {
        float tm = -1e30f;
#pragma unroll
        for (int c = 0; c < 4; ++c)
#pragma unroll
          for (int r = 0; r < 4; ++r) tm = fmaxf(tm, s[g][c][r]);
        tm = fmaxf(tm, __shfl_xor(tm, 16));
        tm = fmaxf(tm, __shfl_xor(tm, 32));
        const float mn = fmaxf(mrow[g], tm);
        const float fac = fexp2(mrow[g] - mn);  // log2-domain
        mrow[g] = mn;
        float sum = 0.f;
#pragma unroll
        for (int c = 0; c < 4; ++c) {
          bf16x4 pc;
#pragma unroll
          for (int r = 0; r < 4; ++r) {
            const float p = fexp2(s[g][c][r] - mn);
            sum += p;
            pc[r] = (__bf16)p;
          }
          const int bo = (c * 32 + fq * 8) ^ swz;
          *reinterpret_cast<bf16x4*>(sPb + (g * 16 + fr) * 128 + bo) = pc;
        }
        sum += __shfl_xor(sum, 16);
        sum += __shfl_xor(sum, 32);
        lrow[g] = lrow[g] * fac + sum;
#pragma unroll
        for (int dt = 0; dt < 4; ++dt)
#pragma unroll
          for (int r = 0; r < 4; ++r) acc[g][dt][r] *= fac;

        bf16x8 pa[2];
#pragma unroll
        for (int ks = 0; ks < 2; ++ks) {
          const int bo = (ks * 64 + fq * 16) ^ swz;
          pa[ks] = *reinterpret_cast<const bf16x8*>(sPb +
                                                    (g * 16 + fr) * 128 + bo);
        }

        __builtin_amdgcn_s_setprio(1);
#pragma unroll
        for (int dt = 0; dt < 4; ++dt) {
          const int row = dt * 16 + fr;
          bf16x8 vf0 = *reinterpret_cast<const bf16x8*>(
              vb + row * 128 + ((fq * 16) ^ swz));
          bf16x8 vf1 = *reinterpret_cast<const bf16x8*>(
              vb + row * 128 + ((fq * 16 + 64) ^ swz));
          acc[g][dt] = mfma16(vf0, pa[0], acc[g][dt]);
          acc[g][dt] = mfma16(vf1, pa[1], acc[g][dt]);
        }
        __builtin_amdgcn_s_setprio(0);
      }
    }

    __syncthreads();
    cur ^= 1;
  }

  const int b = bh / H_, h = bh % H_;
#pragma unroll
  for (int g = 0; g < 2; ++g) {
    const float inv_l = 1.0f / lrow[g];
    const int qrow = qbw + g * 16 + fr;
#pragma unroll
    for (int dt = 0; dt < 4; ++dt) {
      bf16x4 ov;
#pragma unroll
      for (int r = 0; r < 4; ++r) ov[r] = (__bf16)(acc[g][dt][r] * inv_l);
      *reinterpret_cast<bf16x4*>(
          &C[((size_t)(b * S_ + qrow)) * D_ + h * HD_ + dt * 16 + fq * 4]) =
          ov;
    }
  }
}

// ---------------- workspace layout (bf16 elements) ---------------------------
static constexpr size_t XB_OFF = 0;
static constexpr size_t WQ_OFF = XB_OFF + (size_t)T_ * D_;
static constexpr size_t WK_OFF = WQ_OFF + (size_t)D_ * D_;
static constexpr size_t WV_OFF = WK_OFF + (size_t)D_ * D_;
static constexpr size_t WO_OFF = WV_OFF + (size_t)D_ * D_;
static constexpr size_t Q_OFF = WO_OFF + (size_t)D_ * D_;
static constexpr size_t K_OFF = Q_OFF + (size_t)T_ * D_;
static constexpr size_t V_OFF = K_OFF + (size_t)T_ * D_;
static constexpr size_t C_OFF = V_OFF + (size_t)T_ * D_;

extern "C" void kernel_launch(void* const* d_in, const int* in_sizes, int n_in,
                              void* d_out, int out_size, void* d_ws,
                              size_t ws_size, hipStream_t stream) {
  const float* x = (const float*)d_in[0];
  const float* wq = (const float*)d_in[1];
  const float* wk = (const float*)d_in[2];
  const float* wv = (const float*)d_in[3];
  const float* wo = (const float*)d_in[4];
  const float* bo = (const float*)d_in[5];
  float* out = (float*)d_out;
  __bf16* ws = (__bf16*)d_ws;

  __bf16* xb = ws + XB_OFF;
  __bf16* wqb = ws + WQ_OFF;
  __bf16* wkb = ws + WK_OFF;
  __bf16* wvb = ws + WV_OFF;
  __bf16* wob = ws + WO_OFF;
  __bf16* qbuf = ws + Q_OFF;
  __bf16* kbuf = ws + K_OFF;
  __bf16* vbuf = ws + V_OFF;
  __bf16* cbuf = ws + C_OFF;

  {
    int n4 = T_ * D_ / 4;
    cvt_f32_bf16<<<(n4 + 255) / 256, 256, 0, stream>>>(x, xb, n4, 1.0f);
    n4 = D_ * D_ / 4;
    cvt_f32_bf16<<<(n4 + 255) / 256, 256, 0, stream>>>(wq, wqb, n4, 1.0f);
    // fold 1/sqrt(64) * log2(e) into K: scores emerge in log2-domain
    cvt_f32_bf16<<<(n4 + 255) / 256, 256, 0, stream>>>(wk, wkb, n4,
                                                       0.18033688f);
    cvt_f32_bf16<<<(n4 + 255) / 256, 256, 0, stream>>>(wv, wvb, n4, 1.0f);
    cvt_f32_bf16<<<(n4 + 255) / 256, 256, 0, stream>>>(wo, wob, n4, 1.0f);
  }

  gemm_bt<0><<<dim3(64, 18), 256, 0, stream>>>(
      xb, wqb, wkb, wvb, qbuf, kbuf, vbuf, nullptr, nullptr);

  attn_kernel<<<dim3(768), 256, 0, stream>>>(qbuf, kbuf, vbuf, cbuf);

  gemm_bt<1><<<dim3(64, 6), 256, 0, stream>>>(
      cbuf, wob, nullptr, nullptr, nullptr, nullptr, nullptr, out, bo);
}

// Round 16
// 128.542 us; speedup vs baseline: 1.4210x; 1.1451x over previous
//
#include <hip/hip_runtime.h>

#define B_ 4
#define S_ 2048
#define D_ 768
#define H_ 12
#define HD_ 64
#define T_ (B_ * S_)  // 8192

typedef __bf16 bf16x8 __attribute__((ext_vector_type(8)));
typedef __bf16 bf16x4 __attribute__((ext_vector_type(4)));
typedef float  f32x4  __attribute__((ext_vector_type(4)));

__device__ __forceinline__ f32x4 mfma16(bf16x8 a, bf16x8 b, f32x4 c) {
  return __builtin_amdgcn_mfma_f32_16x16x32_bf16(a, b, c, 0, 0, 0);
}

// 2^x via v_exp_f32 (scores are pre-scaled by log2e at weight-convert time)
__device__ __forceinline__ float fexp2(float x) {
  float r;
  asm("v_exp_f32 %0, %1" : "=v"(r) : "v"(x));
  return r;
}

// async global->LDS, 16B per lane. LDS dest is wave-uniform base + lane*16.
__device__ __forceinline__ void gload16(const __bf16* g, __bf16* lds) {
  __builtin_amdgcn_global_load_lds(
      (__attribute__((address_space(1))) void*)g,
      (__attribute__((address_space(3))) void*)lds, 16, 0, 0);
}

// ---------------- fused fp32 -> bf16 convert (x + 4 weights, 1 launch) -------
// Outputs are contiguous in ws (XB|WQ|WK|WV|WO), so out index == flat index.
// wk gets 1/sqrt(64)*log2(e) folded in (scores emerge in log2-domain).
__global__ void cvt_all(const float* __restrict__ x,
                        const float* __restrict__ wq,
                        const float* __restrict__ wk,
                        const float* __restrict__ wv,
                        const float* __restrict__ wo,
                        __bf16* __restrict__ out) {
  constexpr int XN4 = T_ * D_ / 4;
  constexpr int WN4 = D_ * D_ / 4;
  const int i = blockIdx.x * blockDim.x + threadIdx.x;
  if (i >= XN4 + 4 * WN4) return;
  const float* src;
  int k;
  float scale = 1.0f;
  if (i < XN4) {
    src = x;
    k = i;
  } else {
    const int j = i - XN4;
    const int wsel = j / WN4;
    k = j - wsel * WN4;
    src = (wsel == 0) ? wq : (wsel == 1) ? wk : (wsel == 2) ? wv : wo;
    if (wsel == 1) scale = 0.18033688f;  // 0.125 * log2(e)
  }
  const float4 v = reinterpret_cast<const float4*>(src)[k];
  bf16x4 o;
  o[0] = (__bf16)(v.x * scale);
  o[1] = (__bf16)(v.y * scale);
  o[2] = (__bf16)(v.z * scale);
  o[3] = (__bf16)(v.w * scale);
  reinterpret_cast<bf16x4*>(out)[i] = o;
}

// ---------------- GEMM: C[m][n] = sum_k A[m][k] * W[n][k]  (B^T layout) ------
// r14-exact structure (passed, best GEMM measured): 128x128 tile, BK=64,
// 2-deep counted-vmcnt pipeline, XOR-swizzled LDS (row&7)<<4 via pre-swizzled
// global source, XCD-slab remap. r16 change: V-scatter epilogue vectorized
// (4 consecutive s per lane -> one 8-B bf16x4 store instead of 4x 2-B).
template <int MODE>
__global__ __launch_bounds__(256)
__attribute__((amdgpu_waves_per_eu(2)))
void gemm_bt(const __bf16* __restrict__ A,
             const __bf16* __restrict__ W0, const __bf16* __restrict__ W1,
             const __bf16* __restrict__ W2,
             __bf16* __restrict__ Oq, __bf16* __restrict__ Ok,
             __bf16* __restrict__ Ov,
             float* __restrict__ fout, const float* __restrict__ bias) {
  constexpr int K = D_;       // 768
  constexpr int NT = K / 64;  // 12 K-tiles
  __shared__ __align__(16) __bf16 sA[2][128 * 64];
  __shared__ __align__(16) __bf16 sB[2][128 * 64];

  const int tid = threadIdx.x;
  const int l = tid & 63;
  const int w = tid >> 6;

  // XCD-slab remap: mtile = xcd*8 + (q&7), panel changes slowest per XCD.
  const int flat = blockIdx.y * 64 + blockIdx.x;
  const int xcd = flat & 7;
  const int q = flat >> 3;
  const int mtile = xcd * 8 + (q & 7);
  const int pan = q >> 3;  // [0,18) MODE0, [0,6) MODE1
  const int m0 = mtile * 128;

  int mat, n0;
  const __bf16* Wm;
  if (MODE == 0) {
    mat = pan / 6;
    n0 = (pan % 6) * 128;
    Wm = (mat == 0) ? W0 : (mat == 1) ? W1 : W2;
  } else {
    mat = 0;
    n0 = pan * 128;
    Wm = W0;
  }

  // staging: chunk c (0..15) = rows [c*8, c*8+8) x 64 k (1 KB). Wave w stages
  // chunks 4w..4w+3 of A and B. Lane l -> row c*8 + (l>>3), 16B slot (l&7);
  // source col pre-swizzled so LDS[r][slot] = G[r][slot ^ (r&7)].
  const int srow = l >> 3;                // 0..7
  const int scol = ((l & 7) ^ srow) * 8;  // source col (elements)
  const __bf16* gA[4];
  const __bf16* gB[4];
#pragma unroll
  for (int i = 0; i < 4; ++i) {
    const int c = w * 4 + i;
    gA[i] = A + (size_t)(m0 + c * 8 + srow) * K + scol;
    gB[i] = Wm + (size_t)(n0 + c * 8 + srow) * K + scol;
  }

  f32x4 acc[4][4] = {};
  const int wr = w >> 1, wc = w & 1;
  const int fr = l & 15, fq = l >> 4;
  const int swz = (fr & 7) << 4;

  // prologue: stage K-tiles 0 and 1 (16 loads/wave in flight)
#pragma unroll
  for (int i = 0; i < 4; ++i) {
    const int c = w * 4 + i;
    gload16(gA[i], &sA[0][c * 512]);
    gload16(gB[i], &sB[0][c * 512]);
  }
#pragma unroll
  for (int i = 0; i < 4; ++i) {
    const int c = w * 4 + i;
    gload16(gA[i] + 64, &sA[1][c * 512]);
    gload16(gB[i] + 64, &sB[1][c * 512]);
  }

  int cur = 0;
  for (int kt = 0; kt < NT; ++kt) {
    // wait for OWN stage(kt) only; stage(kt+1) stays in flight (counted vmcnt)
    if (kt + 1 < NT)
      asm volatile("s_waitcnt vmcnt(8)" ::: "memory");
    else
      asm volatile("s_waitcnt vmcnt(0)" ::: "memory");
    __builtin_amdgcn_s_barrier();  // all waves' stage(kt) landed

    const char* ab = reinterpret_cast<const char*>(&sA[cur][0]);
    const char* bb = reinterpret_cast<const char*>(&sB[cur][0]);
#pragma unroll
    for (int ks = 0; ks < 2; ++ks) {
      bf16x8 af[4], bfr[4];
#pragma unroll
      for (int mi = 0; mi < 4; ++mi)
        af[mi] = *reinterpret_cast<const bf16x8*>(
            ab + (wr * 64 + mi * 16 + fr) * 128 +
            ((ks * 64 + fq * 16) ^ swz));
#pragma unroll
      for (int ni = 0; ni < 4; ++ni)
        bfr[ni] = *reinterpret_cast<const bf16x8*>(
            bb + (wc * 64 + ni * 16 + fr) * 128 +
            ((ks * 64 + fq * 16) ^ swz));
#pragma unroll
      for (int mi = 0; mi < 4; ++mi)
#pragma unroll
        for (int ni = 0; ni < 4; ++ni)
          acc[mi][ni] = mfma16(af[mi], bfr[ni], acc[mi][ni]);
    }
    __builtin_amdgcn_s_barrier();  // all waves done reading buf[cur]

    // stage kt+2 into the buffer just freed (2-deep pipeline)
    if (kt + 2 < NT) {
      const int ko = (kt + 2) * 64;
#pragma unroll
      for (int i = 0; i < 4; ++i) {
        const int c = w * 4 + i;
        gload16(gA[i] + ko, &sA[cur][c * 512]);
        gload16(gB[i] + ko, &sB[cur][c * 512]);
      }
    }
    cur ^= 1;
  }

  // epilogue
#pragma unroll
  for (int mi = 0; mi < 4; ++mi) {
    const int mbase = m0 + wr * 64 + mi * 16 + fq * 4;
#pragma unroll
    for (int ni = 0; ni < 4; ++ni) {
      const int o = n0 + wc * 64 + ni * 16 + fr;
      if (MODE == 1) {
#pragma unroll
        for (int r = 0; r < 4; ++r)
          fout[(mbase + r) * D_ + o] = acc[mi][ni][r] + bias[o];
      } else {
        const int h = o >> 6, hd = o & 63;
        const int b = mbase >> 11, s = mbase & (S_ - 1);
        if (mat == 2) {
          // V^T: 4 consecutive s per lane -> one aligned 8-B store
          bf16x4 vv;
#pragma unroll
          for (int r = 0; r < 4; ++r) vv[r] = (__bf16)acc[mi][ni][r];
          *reinterpret_cast<bf16x4*>(
              &Ov[((size_t)((b * H_ + h) * HD_ + hd)) * S_ + s]) = vv;
        } else {
          __bf16* dst = (mat == 0) ? Oq : Ok;
#pragma unroll
          for (int r = 0; r < 4; ++r)
            dst[((size_t)((b * H_ + h) * S_ + s + r)) * HD_ + hd] =
                (__bf16)acc[mi][ni][r];
        }
      }
    }
  }
}

// ---------------- causal flash attention: 4-warp block, LDS-staged K/V --------
// (r11/r14-exact, passed at ~35 us)
__global__ __launch_bounds__(256)
__attribute__((amdgpu_waves_per_eu(3, 4)))
void attn_kernel(const __bf16* __restrict__ Q, const __bf16* __restrict__ Kt,
                 const __bf16* __restrict__ Vt, __bf16* __restrict__ C) {
  __shared__ __align__(16) __bf16 sK[2][64 * 64];  // [kv][hd], swizzled
  __shared__ __align__(16) __bf16 sV[2][64 * 64];  // V^T [hd][kv], swizzled
  __shared__ __align__(16) __bf16 sP[4][32 * 64];  // per-warp P, swizzled

  const int tid = threadIdx.x;
  const int l = tid & 63;
  const int w = tid >> 6;
  const int fr = l & 15, fq = l >> 4;
  const int bx = blockIdx.x;
  const int xcd = bx & 7;
  const int j = bx >> 3;             // [0, 96)
  const int bh = xcd + 8 * (j % 6);  // head in [0, 48)
  const int qtile = 15 - j / 6;      // [0, 16), deep first
  const int qb = qtile * 128;
  const int qbw = qb + w * 32;  // this warp's 32 q-rows

  const __bf16* qh = Q + (size_t)bh * S_ * HD_;
  const __bf16* kh = Kt + (size_t)bh * S_ * HD_;
  const __bf16* vh = Vt + (size_t)bh * HD_ * S_;
  char* sPb = reinterpret_cast<char*>(&sP[w][0]);

  const int srow = l >> 3;                       // 0..7
  const int scol = ((l & 7) * 8) ^ (srow << 3);  // pre-swizzled source col
  const int swz = (fr & 7) << 4;                 // read-side XOR (bytes)

  bf16x8 qf[2][2];
#pragma unroll
  for (int g = 0; g < 2; ++g)
#pragma unroll
    for (int ks = 0; ks < 2; ++ks)
      qf[g][ks] = *reinterpret_cast<const bf16x8*>(
          &qh[(size_t)(qbw + g * 16 + fr) * HD_ + ks * 32 + fq * 8]);

  f32x4 acc[2][4] = {};
  float mrow[2] = {-1e30f, -1e30f}, lrow[2] = {0.f, 0.f};

  const int nt = qb / 64 + 2;  // ceil((qb+128)/64)
  int cur = 0;

  {
    const int q0 = 2 * w, q1 = 2 * w + 1;
    gload16(kh + (size_t)(q0 * 8 + srow) * HD_ + scol, &sK[0][q0 * 512]);
    gload16(kh + (size_t)(q1 * 8 + srow) * HD_ + scol, &sK[0][q1 * 512]);
    gload16(vh + (size_t)(q0 * 8 + srow) * S_ + scol, &sV[0][q0 * 512]);
    gload16(vh + (size_t)(q1 * 8 + srow) * S_ + scol, &sV[0][q1 * 512]);
  }
  __syncthreads();

  for (int t = 0; t < nt; ++t) {
    const int kv0 = t * 64;
    if (t + 1 < nt) {
      const int kvn = kv0 + 64;
      const int q0 = 2 * w, q1 = 2 * w + 1;
      gload16(kh + (size_t)(kvn + q0 * 8 + srow) * HD_ + scol,
              &sK[cur ^ 1][q0 * 512]);
      gload16(kh + (size_t)(kvn + q1 * 8 + srow) * HD_ + scol,
              &sK[cur ^ 1][q1 * 512]);
      gload16(vh + (size_t)(q0 * 8 + srow) * S_ + kvn + scol,
              &sV[cur ^ 1][q0 * 512]);
      gload16(vh + (size_t)(q1 * 8 + srow) * S_ + kvn + scol,
              &sV[cur ^ 1][q1 * 512]);
    }

    if (kv0 <= qbw + 31) {
      const char* kb = reinterpret_cast<const char*>(&sK[cur][0]);
      const char* vb = reinterpret_cast<const char*>(&sV[cur][0]);

      f32x4 s[2][4];
      __builtin_amdgcn_s_setprio(1);
#pragma unroll
      for (int c = 0; c < 4; ++c) {
        const int row = c * 16 + fr;
        bf16x8 kf0 = *reinterpret_cast<const bf16x8*>(
            kb + row * 128 + ((fq * 16) ^ swz));
        bf16x8 kf1 = *reinterpret_cast<const bf16x8*>(
            kb + row * 128 + ((fq * 16 + 64) ^ swz));
#pragma unroll
        for (int g = 0; g < 2; ++g) {
          f32x4 z = {};
          z = mfma16(kf0, qf[g][0], z);
          z = mfma16(kf1, qf[g][1], z);
          s[g][c] = z;
        }
      }
      __builtin_amdgcn_s_setprio(0);

      if (kv0 + 63 > qbw) {
#pragma unroll
        for (int g = 0; g < 2; ++g) {
          const int qi = qbw + g * 16 + fr;
#pragma unroll
          for (int c = 0; c < 4; ++c)
#pragma unroll
            for (int r = 0; r < 4; ++r) {
              const int kvi = kv0 + c * 16 + fq * 4 + r;
              if (kvi > qi) s[g][c][r] = -1e30f;
            }
        }
      }

#pragma unroll
      for (int g = 0; g < 2; ++g) {
        float tm = -1e30f;
#pragma unroll
        for (int c = 0; c < 4; ++c)
#pragma unroll
          for (int r = 0; r < 4; ++r) tm = fmaxf(tm, s[g][c][r]);
        tm = fmaxf(tm, __shfl_xor(tm, 16));
        tm = fmaxf(tm, __shfl_xor(tm, 32));
        const float mn = fmaxf(mrow[g], tm);
        const float fac = fexp2(mrow[g] - mn);  // log2-domain
        mrow[g] = mn;
        float sum = 0.f;
#pragma unroll
        for (int c = 0; c < 4; ++c) {
          bf16x4 pc;
#pragma unroll
          for (int r = 0; r < 4; ++r) {
            const float p = fexp2(s[g][c][r] - mn);
            sum += p;
            pc[r] = (__bf16)p;
          }
          const int bo = (c * 32 + fq * 8) ^ swz;
          *reinterpret_cast<bf16x4*>(sPb + (g * 16 + fr) * 128 + bo) = pc;
        }
        sum += __shfl_xor(sum, 16);
        sum += __shfl_xor(sum, 32);
        lrow[g] = lrow[g] * fac + sum;
#pragma unroll
        for (int dt = 0; dt < 4; ++dt)
#pragma unroll
          for (int r = 0; r < 4; ++r) acc[g][dt][r] *= fac;

        bf16x8 pa[2];
#pragma unroll
        for (int ks = 0; ks < 2; ++ks) {
          const int bo = (ks * 64 + fq * 16) ^ swz;
          pa[ks] = *reinterpret_cast<const bf16x8*>(sPb +
                                                    (g * 16 + fr) * 128 + bo);
        }

        __builtin_amdgcn_s_setprio(1);
#pragma unroll
        for (int dt = 0; dt < 4; ++dt) {
          const int row = dt * 16 + fr;
          bf16x8 vf0 = *reinterpret_cast<const bf16x8*>(
              vb + row * 128 + ((fq * 16) ^ swz));
          bf16x8 vf1 = *reinterpret_cast<const bf16x8*>(
              vb + row * 128 + ((fq * 16 + 64) ^ swz));
          acc[g][dt] = mfma16(vf0, pa[0], acc[g][dt]);
          acc[g][dt] = mfma16(vf1, pa[1], acc[g][dt]);
        }
        __builtin_amdgcn_s_setprio(0);
      }
    }

    __syncthreads();
    cur ^= 1;
  }

  const int b = bh / H_, h = bh % H_;
#pragma unroll
  for (int g = 0; g < 2; ++g) {
    const float inv_l = 1.0f / lrow[g];
    const int qrow = qbw + g * 16 + fr;
#pragma unroll
    for (int dt = 0; dt < 4; ++dt) {
      bf16x4 ov;
#pragma unroll
      for (int r = 0; r < 4; ++r) ov[r] = (__bf16)(acc[g][dt][r] * inv_l);
      *reinterpret_cast<bf16x4*>(
          &C[((size_t)(b * S_ + qrow)) * D_ + h * HD_ + dt * 16 + fq * 4]) =
          ov;
    }
  }
}

// ---------------- workspace layout (bf16 elements) ---------------------------
static constexpr size_t XB_OFF = 0;
static constexpr size_t WQ_OFF = XB_OFF + (size_t)T_ * D_;
static constexpr size_t WK_OFF = WQ_OFF + (size_t)D_ * D_;
static constexpr size_t WV_OFF = WK_OFF + (size_t)D_ * D_;
static constexpr size_t WO_OFF = WV_OFF + (size_t)D_ * D_;
static constexpr size_t Q_OFF = WO_OFF + (size_t)D_ * D_;
static constexpr size_t K_OFF = Q_OFF + (size_t)T_ * D_;
static constexpr size_t V_OFF = K_OFF + (size_t)T_ * D_;
static constexpr size_t C_OFF = V_OFF + (size_t)T_ * D_;

extern "C" void kernel_launch(void* const* d_in, const int* in_sizes, int n_in,
                              void* d_out, int out_size, void* d_ws,
                              size_t ws_size, hipStream_t stream) {
  const float* x = (const float*)d_in[0];
  const float* wq = (const float*)d_in[1];
  const float* wk = (const float*)d_in[2];
  const float* wv = (const float*)d_in[3];
  const float* wo = (const float*)d_in[4];
  const float* bo = (const float*)d_in[5];
  float* out = (float*)d_out;
  __bf16* ws = (__bf16*)d_ws;

  __bf16* xb = ws + XB_OFF;
  __bf16* wqb = ws + WQ_OFF;
  __bf16* wkb = ws + WK_OFF;
  __bf16* wvb = ws + WV_OFF;
  __bf16* wob = ws + WO_OFF;
  __bf16* qbuf = ws + Q_OFF;
  __bf16* kbuf = ws + K_OFF;
  __bf16* vbuf = ws + V_OFF;
  __bf16* cbuf = ws + C_OFF;

  {
    constexpr int n4 = T_ * D_ / 4 + 4 * (D_ * D_ / 4);
    cvt_all<<<(n4 + 255) / 256, 256, 0, stream>>>(x, wq, wk, wv, wo, ws);
  }

  gemm_bt<0><<<dim3(64, 18), 256, 0, stream>>>(
      xb, wqb, wkb, wvb, qbuf, kbuf, vbuf, nullptr, nullptr);

  attn_kernel<<<dim3(768), 256, 0, stream>>>(qbuf, kbuf, vbuf, cbuf);

  gemm_bt<1><<<dim3(64, 6), 256, 0, stream>>>(
      cbuf, wob, nullptr, nullptr, nullptr, nullptr, nullptr, out, bo);
}